// Round 1
// baseline (97.482 us; speedup 1.0000x reference)
//
#include <hip/hip_runtime.h>
#include <hip/hip_bf16.h>
#include <math.h>

#define NB 512
#define NQ 30
#define ND 512
#define NE 128
#define NK 21
#define DROW 136      // bf16 elems per LDS row (128 + 8 pad -> 272B, 16B aligned, 2-way bank alias = free)
#define NTHREADS 512

typedef __attribute__((ext_vector_type(4))) float f32x4;
typedef __attribute__((ext_vector_type(8))) short short8;

__device__ __forceinline__ unsigned short f2bf(float f) {
  unsigned int x = __builtin_bit_cast(unsigned int, f);
  x = (x + 0x7fffu + ((x >> 16) & 1u)) >> 16;   // RNE
  return (unsigned short)x;
}

__global__ __launch_bounds__(NTHREADS) void knrm_kernel(
    const int* __restrict__ query, const int* __restrict__ doc,
    const float* __restrict__ emb,
    const float* __restrict__ w1, const float* __restrict__ b1,
    const float* __restrict__ w2, const float* __restrict__ b2,
    const float* __restrict__ w3, const float* __restrict__ b3,
    float* __restrict__ out)
{
  extern __shared__ unsigned char smem_raw[];
  unsigned short* dnor = (unsigned short*)smem_raw;     // [ND][DROW] bf16 normalized doc
  unsigned short* qnor = dnor + ND * DROW;              // [32][DROW] bf16 normalized query (rows 30,31 zero)
  float* S   = (float*)(qnor + 32 * DROW);              // [32][NK] kernel sums
  int*   did = (int*)(S + 32 * NK);                     // [ND]
  int*   qid = did + ND;                                // [32]
  float* km  = (float*)(qid + 32);                      // [NK]
  float* h1  = km + NK;                                 // [10]
  float* h2  = h1 + 10;                                 // [5]

  const int t = threadIdx.x;
  const int b = blockIdx.x;

  for (int i = t; i < 32 * NK; i += NTHREADS) S[i] = 0.0f;
  if (t < ND) did[t] = doc[b * ND + t];
  if (t < 32) qid[t] = (t < NQ) ? query[b * NQ + t] : -1;

  const int jq = t & 3;  // 4 lanes cooperate per row

  // ---- gather + normalize doc rows into LDS (bf16) ----
  for (int round = 0; round < 4; ++round) {
    const int r = round * 128 + (t >> 2);
    const int id = doc[b * ND + r];
    const float* src = emb + (size_t)id * NE;
    float4 v[8];
    float ssq = 0.0f;
#pragma unroll
    for (int c = 0; c < 8; ++c) {
      v[c] = *(const float4*)(src + c * 16 + jq * 4);
      ssq += v[c].x * v[c].x + v[c].y * v[c].y + v[c].z * v[c].z + v[c].w * v[c].w;
    }
    ssq += __shfl_xor(ssq, 1);
    ssq += __shfl_xor(ssq, 2);
    const float sc = 1.0f / fmaxf(sqrtf(ssq), 1e-12f);
    unsigned short* dst = dnor + r * DROW;
#pragma unroll
    for (int c = 0; c < 8; ++c) {
      ushort4 o;
      o.x = f2bf(v[c].x * sc); o.y = f2bf(v[c].y * sc);
      o.z = f2bf(v[c].z * sc); o.w = f2bf(v[c].w * sc);
      *(ushort4*)(dst + c * 16 + jq * 4) = o;
    }
  }

  // ---- gather + normalize query rows (pad rows 30,31 with zeros) ----
  if (t < 128) {
    const int r = t >> 2;
    unsigned short* dst = qnor + r * DROW;
    if (r < NQ) {
      const int id = query[b * NQ + r];
      const float* src = emb + (size_t)id * NE;
      float4 v[8];
      float ssq = 0.0f;
#pragma unroll
      for (int c = 0; c < 8; ++c) {
        v[c] = *(const float4*)(src + c * 16 + jq * 4);
        ssq += v[c].x * v[c].x + v[c].y * v[c].y + v[c].z * v[c].z + v[c].w * v[c].w;
      }
      ssq += __shfl_xor(ssq, 1);
      ssq += __shfl_xor(ssq, 2);
      const float sc = 1.0f / fmaxf(sqrtf(ssq), 1e-12f);
#pragma unroll
      for (int c = 0; c < 8; ++c) {
        ushort4 o;
        o.x = f2bf(v[c].x * sc); o.y = f2bf(v[c].y * sc);
        o.z = f2bf(v[c].z * sc); o.w = f2bf(v[c].w * sc);
        *(ushort4*)(dst + c * 16 + jq * 4) = o;
      }
    } else {
      ushort4 z; z.x = z.y = z.z = z.w = 0;
#pragma unroll
      for (int c = 0; c < 8; ++c) *(ushort4*)(dst + c * 16 + jq * 4) = z;
    }
  }
  __syncthreads();

  // ---- exact-match kernel (mu=1, sigma=0.001): integer ID equality ----
  {
    const int d0 = did[t];
#pragma unroll 1
    for (int q = 0; q < NQ; ++q)
      if (d0 == qid[q]) atomicAdd(&S[q * NK + 20], 1.0f);
  }

  // ---- mm^T = Dn x Qn^T via MFMA: C[d][q], so the d-sum is lane-local ----
  const int wave = t >> 6;
  const int lane = t & 63;
  const int qt   = wave & 1;   // q-col tile (0: q 0-15, 1: q 16-31)
  const int dg   = wave >> 1;  // d-row group of 128
  const int lrow = lane & 15;
  const int lgrp = lane >> 4;

  f32x4 acc[8];
#pragma unroll
  for (int i = 0; i < 8; ++i) acc[i] = (f32x4){0.f, 0.f, 0.f, 0.f};

  const unsigned short* qbase = qnor + (qt * 16 + lrow) * DROW + lgrp * 8;
  const unsigned short* abase = dnor + (dg * 128 + lrow) * DROW + lgrp * 8;

#pragma unroll
  for (int ks = 0; ks < 4; ++ks) {
    short8 bq = *(const short8*)(qbase + ks * 32);
#pragma unroll
    for (int dt = 0; dt < 8; ++dt) {
      short8 a = *(const short8*)(abase + dt * 16 * DROW + ks * 32);
      acc[dt] = __builtin_amdgcn_mfma_f32_16x16x32_bf16(a, bq, acc[dt], 0, 0, 0);
    }
  }

  // each lane: 32 mm values (its 32 d-rows) for one q column
  float mm[32];
#pragma unroll
  for (int dt = 0; dt < 8; ++dt)
#pragma unroll
    for (int r = 0; r < 4; ++r) mm[dt * 4 + r] = acc[dt][r];

  const float Cc = -72.13475204444817f;  // -1/(2*0.1^2*ln2)
  float Aq[32];
#pragma unroll
  for (int i = 0; i < 32; ++i) Aq[i] = mm[i] * mm[i] * Cc;

  const int q = qt * 16 + lrow;
#pragma unroll 1
  for (int k = 0; k < 20; ++k) {
    const float mu = -0.95f + 0.1f * (float)k;
    const float bk = -2.0f * Cc * mu;
    const float gk = Cc * mu * mu;
    float s0 = 0.f, s1 = 0.f, s2 = 0.f, s3 = 0.f;
#pragma unroll
    for (int i = 0; i < 32; i += 4) {
      s0 += exp2f(fmaf(mm[i    ], bk, Aq[i    ]) + gk);
      s1 += exp2f(fmaf(mm[i + 1], bk, Aq[i + 1]) + gk);
      s2 += exp2f(fmaf(mm[i + 2], bk, Aq[i + 2]) + gk);
      s3 += exp2f(fmaf(mm[i + 3], bk, Aq[i + 3]) + gk);
    }
    float s = (s0 + s1) + (s2 + s3);
    s += __shfl_xor(s, 16);
    s += __shfl_xor(s, 32);
    if (lgrp == 0 && q < NQ) atomicAdd(&S[q * NK + k], s);
  }
  __syncthreads();

  // ---- epilogue: km = sum_q log1p(S), then MLP 21->10->5->1 ----
  if (t < NK) {
    float s = 0.f;
    for (int qq = 0; qq < NQ; ++qq) s += log1pf(S[qq * NK + t]);
    km[t] = s;
  }
  __syncthreads();
  if (t < 10) {
    float a = b1[t];
#pragma unroll 1
    for (int k2 = 0; k2 < NK; ++k2) a = fmaf(km[k2], w1[k2 * 10 + t], a);
    h1[t] = fmaxf(a, 0.f);
  }
  __syncthreads();
  if (t < 5) {
    float a = b2[t];
#pragma unroll 1
    for (int k2 = 0; k2 < 10; ++k2) a = fmaf(h1[k2], w2[k2 * 5 + t], a);
    h2[t] = fmaxf(a, 0.f);
  }
  __syncthreads();
  if (t == 0) {
    float a = b3[0];
#pragma unroll 1
    for (int k2 = 0; k2 < 5; ++k2) a = fmaf(h2[k2], w3[k2], a);
    out[b] = a;
  }
}

extern "C" void kernel_launch(void* const* d_in, const int* in_sizes, int n_in,
                              void* d_out, int out_size, void* d_ws, size_t ws_size,
                              hipStream_t stream) {
  const int*   query = (const int*)d_in[0];
  const int*   doc   = (const int*)d_in[1];
  const float* emb   = (const float*)d_in[2];
  const float* w1    = (const float*)d_in[3];
  const float* b1    = (const float*)d_in[4];
  const float* w2    = (const float*)d_in[5];
  const float* b2    = (const float*)d_in[6];
  const float* w3    = (const float*)d_in[7];
  const float* b3    = (const float*)d_in[8];
  float* out = (float*)d_out;

  const size_t sh = (size_t)(ND + 32) * DROW * 2   // dnor + qnor (bf16)
                  + (size_t)32 * NK * 4            // S
                  + (size_t)(ND + 32) * 4          // did + qid
                  + (size_t)(NK + 10 + 5) * 4;     // km + h1 + h2

  hipFuncSetAttribute((const void*)knrm_kernel,
                      hipFuncAttributeMaxDynamicSharedMemorySize, (int)sh);
  knrm_kernel<<<dim3(NB), dim3(NTHREADS), sh, stream>>>(
      query, doc, emb, w1, b1, w2, b2, w3, b3, out);
}

// Round 2
// 83.707 us; speedup vs baseline: 1.1646x; 1.1646x over previous
//
#include <hip/hip_runtime.h>
#include <hip/hip_bf16.h>
#include <math.h>

#define NB 512
#define NQ 30
#define ND 512
#define NE 128
#define NK 21
#define VOCAB 50000
#define QROW 136   // padded bf16 row stride for query LDS (272B: 2-way bank alias = free)

typedef __attribute__((ext_vector_type(4))) float f32x4;
typedef __attribute__((ext_vector_type(8))) short short8;

// normalized vocab table, bf16 (12.8 MB, L3-resident). Rewritten every launch.
__device__ unsigned short g_norm[(size_t)VOCAB * NE];

__device__ __forceinline__ unsigned short f2bf(float f) {
  unsigned int x = __builtin_bit_cast(unsigned int, f);
  x = (x + 0x7fffu + ((x >> 16) & 1u)) >> 16;   // RNE
  return (unsigned short)x;
}

// ---------------- kernel 1: normalize whole vocab to bf16 ----------------
__global__ __launch_bounds__(256) void norm_kernel(const float* __restrict__ emb) {
  const int t = threadIdx.x;
  const int row = blockIdx.x * 64 + (t >> 2);
  if (row >= VOCAB) return;
  const int jq = t & 3;
  const float* src = emb + (size_t)row * NE;
  float4 v[8];
  float ssq = 0.0f;
#pragma unroll
  for (int c = 0; c < 8; ++c) {
    v[c] = *(const float4*)(src + c * 16 + jq * 4);
    ssq += v[c].x * v[c].x + v[c].y * v[c].y + v[c].z * v[c].z + v[c].w * v[c].w;
  }
  ssq += __shfl_xor(ssq, 1);
  ssq += __shfl_xor(ssq, 2);
  const float sc = 1.0f / fmaxf(sqrtf(ssq), 1e-12f);
  unsigned short* dst = g_norm + (size_t)row * NE;
#pragma unroll
  for (int c = 0; c < 8; ++c) {
    ushort4 o;
    o.x = f2bf(v[c].x * sc); o.y = f2bf(v[c].y * sc);
    o.z = f2bf(v[c].z * sc); o.w = f2bf(v[c].w * sc);
    *(ushort4*)(dst + c * 16 + jq * 4) = o;
  }
}

// ---------------- kernel 2: fused KNRM ----------------
__global__ __launch_bounds__(512) void knrm_main(
    const int* __restrict__ query, const int* __restrict__ doc,
    const float* __restrict__ w1, const float* __restrict__ b1,
    const float* __restrict__ w2, const float* __restrict__ b2,
    const float* __restrict__ w3, const float* __restrict__ b3,
    float* __restrict__ out)
{
  __shared__ unsigned short qnor[32 * QROW];  // normalized query rows (30 + 2 zero)
  __shared__ float Sw[8][32][NK];             // per-wave partial kernel sums (k<20 used)
  __shared__ float Sex[32];                   // exact-match counts
  __shared__ int   qid[32];
  __shared__ float km[NK], h1[10], h2[5];

  const int t = threadIdx.x;
  const int b = blockIdx.x;
  const int wave = t >> 6, lane = t & 63;
  const int lrow = lane & 15, lgrp = lane >> 4;

  if (t < 32) {
    qid[t] = (t < NQ) ? query[b * NQ + t] : -1;
    Sex[t] = 0.0f;
  }
  // stage query rows from the normalized table: 16 lanes x 16B per row
  if (t < 480) {
    const int row = t >> 4, j = t & 15;
    const unsigned short* src = g_norm + (size_t)query[b * NQ + row] * NE + j * 8;
    *(short8*)(qnor + row * QROW + j * 8) = *(const short8*)src;
  } else {
    const int idx = t - 480;                 // zero-pad rows 30,31 (data cols only)
    const int row = 30 + (idx >> 4), j = idx & 15;
    *(short8*)(qnor + row * QROW + j * 8) = (short8){0,0,0,0,0,0,0,0};
  }
  __syncthreads();

  // ---- exact-match kernel (mu=1, sigma=0.001): integer ID equality ----
  {
    const int did = doc[b * ND + t];
#pragma unroll 1
    for (int q = 0; q < NQ; ++q)
      if (did == qid[q]) atomicAdd(&Sex[q], 1.0f);   // all +1.0: order-invariant
  }

  // ---- per-lane A-fragment byte offsets into g_norm ----
  const int d0 = wave * 64;
  unsigned aoff[4];
#pragma unroll
  for (int dt = 0; dt < 4; ++dt) {
    const int id = doc[b * ND + d0 + dt * 16 + lrow];
    aoff[dt] = (unsigned)id * (NE * 2) + lgrp * 16;
  }

  // ---- mm^T tiles: C[d][q]; A from global table, B from LDS ----
  f32x4 acc[2][4];
#pragma unroll
  for (int qt = 0; qt < 2; ++qt)
#pragma unroll
    for (int dt = 0; dt < 4; ++dt) acc[qt][dt] = (f32x4){0.f, 0.f, 0.f, 0.f};

  const unsigned char* gbase = (const unsigned char*)g_norm;
#pragma unroll
  for (int ks = 0; ks < 4; ++ks) {
    short8 bq0 = *(const short8*)(qnor + lrow * QROW + ks * 32 + lgrp * 8);
    short8 bq1 = *(const short8*)(qnor + (16 + lrow) * QROW + ks * 32 + lgrp * 8);
#pragma unroll
    for (int dt = 0; dt < 4; ++dt) {
      short8 a = *(const short8*)(gbase + aoff[dt] + ks * 64);
      acc[0][dt] = __builtin_amdgcn_mfma_f32_16x16x32_bf16(a, bq0, acc[0][dt], 0, 0, 0);
      acc[1][dt] = __builtin_amdgcn_mfma_f32_16x16x32_bf16(a, bq1, acc[1][dt], 0, 0, 0);
    }
  }

  // ---- kernel pooling: s_k = 2^{Cc*mu^2} * sum_d exp2(fma(m, bk, Cc*m^2)) ----
  const float Cc = -72.13475204444817f;  // -1/(2*0.1^2*ln2)
#pragma unroll
  for (int qt = 0; qt < 2; ++qt) {
    const int q = qt * 16 + lrow;
    float m[16], P[16];
#pragma unroll
    for (int dt = 0; dt < 4; ++dt)
#pragma unroll
      for (int r = 0; r < 4; ++r) {
        m[dt * 4 + r] = acc[qt][dt][r];
        P[dt * 4 + r] = m[dt * 4 + r] * m[dt * 4 + r] * Cc;
      }
#pragma unroll 1
    for (int k = 0; k < 20; ++k) {
      const float mu  = fmaf(0.1f, (float)k, -0.95f);
      const float bk  = -2.0f * Cc * mu;
      const float sck = __builtin_amdgcn_exp2f(Cc * mu * mu);
      float s0 = 0.f, s1 = 0.f, s2 = 0.f, s3 = 0.f;
#pragma unroll
      for (int i = 0; i < 16; i += 4) {
        s0 += __builtin_amdgcn_exp2f(fmaf(m[i    ], bk, P[i    ]));
        s1 += __builtin_amdgcn_exp2f(fmaf(m[i + 1], bk, P[i + 1]));
        s2 += __builtin_amdgcn_exp2f(fmaf(m[i + 2], bk, P[i + 2]));
        s3 += __builtin_amdgcn_exp2f(fmaf(m[i + 3], bk, P[i + 3]));
      }
      float s = (s0 + s1) + (s2 + s3);
      s += __shfl_xor(s, 16);
      s += __shfl_xor(s, 32);
      if (lgrp == 0 && q < NQ) Sw[wave][q][k] = s * sck;
    }
  }
  __syncthreads();

  // ---- epilogue: km = sum_q log1p(S), then MLP 21->10->5->1 ----
  if (t < NK) {
    float s = 0.f;
    if (t < 20) {
      for (int q = 0; q < NQ; ++q) {
        float v = 0.f;
#pragma unroll
        for (int w = 0; w < 8; ++w) v += Sw[w][q][t];
        s += log1pf(v);
      }
    } else {
      for (int q = 0; q < NQ; ++q) s += log1pf(Sex[q]);
    }
    km[t] = s;
  }
  __syncthreads();
  if (t < 10) {
    float a = b1[t];
#pragma unroll 1
    for (int k2 = 0; k2 < NK; ++k2) a = fmaf(km[k2], w1[k2 * 10 + t], a);
    h1[t] = fmaxf(a, 0.f);
  }
  __syncthreads();
  if (t < 5) {
    float a = b2[t];
#pragma unroll 1
    for (int k2 = 0; k2 < 10; ++k2) a = fmaf(h1[k2], w2[k2 * 5 + t], a);
    h2[t] = fmaxf(a, 0.f);
  }
  __syncthreads();
  if (t == 0) {
    float a = b3[0];
#pragma unroll 1
    for (int k2 = 0; k2 < 5; ++k2) a = fmaf(h2[k2], w3[k2], a);
    out[b] = a;
  }
}

extern "C" void kernel_launch(void* const* d_in, const int* in_sizes, int n_in,
                              void* d_out, int out_size, void* d_ws, size_t ws_size,
                              hipStream_t stream) {
  const int*   query = (const int*)d_in[0];
  const int*   doc   = (const int*)d_in[1];
  const float* emb   = (const float*)d_in[2];
  const float* w1    = (const float*)d_in[3];
  const float* b1    = (const float*)d_in[4];
  const float* w2    = (const float*)d_in[5];
  const float* b2    = (const float*)d_in[6];
  const float* w3    = (const float*)d_in[7];
  const float* b3    = (const float*)d_in[8];
  float* out = (float*)d_out;

  norm_kernel<<<dim3((VOCAB + 63) / 64), dim3(256), 0, stream>>>(emb);
  knrm_main<<<dim3(NB), dim3(512), 0, stream>>>(
      query, doc, w1, b1, w2, b2, w3, b3, out);
}

// Round 3
// 77.090 us; speedup vs baseline: 1.2645x; 1.0858x over previous
//
#include <hip/hip_runtime.h>
#include <hip/hip_bf16.h>
#include <math.h>

#define NB 512
#define NQ 30
#define ND 512
#define NE 128
#define NK 21
#define VOCAB 50000
#define QROW 136   // padded bf16 row stride for query LDS (272B: 2-way bank alias = free)

typedef __attribute__((ext_vector_type(4))) float f32x4;
typedef __attribute__((ext_vector_type(8))) short short8;

// normalized vocab table, bf16 (12.8 MB, L3-resident). Rewritten every launch.
__device__ unsigned short g_norm[(size_t)VOCAB * NE];

__device__ __forceinline__ unsigned short f2bf(float f) {
  unsigned int x = __builtin_bit_cast(unsigned int, f);
  x = (x + 0x7fffu + ((x >> 16) & 1u)) >> 16;   // RNE
  return (unsigned short)x;
}

// ---------------- kernel 1: normalize whole vocab to bf16 ----------------
// 8 rows/block, 32 lanes/row: reads 512B/row contiguous, writes 256B/row.
__global__ __launch_bounds__(256) void norm_kernel(const float* __restrict__ emb) {
  const int t = threadIdx.x;
  const int row = blockIdx.x * 8 + (t >> 5);
  const int j = t & 31;
  const float* src = emb + (size_t)row * NE;
  float4 v = *(const float4*)(src + j * 4);
  float ssq = v.x * v.x + v.y * v.y + v.z * v.z + v.w * v.w;
  ssq += __shfl_xor(ssq, 1);
  ssq += __shfl_xor(ssq, 2);
  ssq += __shfl_xor(ssq, 4);
  ssq += __shfl_xor(ssq, 8);
  ssq += __shfl_xor(ssq, 16);
  const float sc = 1.0f / fmaxf(sqrtf(ssq), 1e-12f);
  ushort4 o;
  o.x = f2bf(v.x * sc); o.y = f2bf(v.y * sc);
  o.z = f2bf(v.z * sc); o.w = f2bf(v.w * sc);
  *(ushort4*)(g_norm + (size_t)row * NE + j * 4) = o;
}

// ---------------- kernel 2: fused KNRM ----------------
// 1024 threads = 16 waves; wave w: qt = w&1 (16 q cols), dg = w>>1 (64 d rows).
__global__ __launch_bounds__(1024, 8) void knrm_main(
    const int* __restrict__ query, const int* __restrict__ doc,
    const float* __restrict__ w1, const float* __restrict__ b1,
    const float* __restrict__ w2, const float* __restrict__ b2,
    const float* __restrict__ w3, const float* __restrict__ b3,
    float* __restrict__ out)
{
  __shared__ unsigned short qnor[32 * QROW];  // normalized query rows (30 + 2 zero)
  __shared__ float Sw[16][16][NK];            // per-wave partial sums (k<20 used)
  __shared__ float Sex[32];                   // exact-match counts
  __shared__ int   qid[32];
  __shared__ float km[NK], h1[10], h2[5];

  const int t = threadIdx.x;
  const int b = blockIdx.x;
  const int wave = t >> 6, lane = t & 63;
  const int lrow = lane & 15, lgrp = lane >> 4;
  const int qt = wave & 1, dg = wave >> 1;

  if (t < 32) {
    qid[t] = (t < NQ) ? query[b * NQ + t] : -1;
    Sex[t] = 0.0f;
  }
  // stage query rows from the normalized table: 16 lanes x 16B per row
  if (t < 480) {
    const int row = t >> 4, j = t & 15;
    const unsigned short* src = g_norm + (size_t)query[b * NQ + row] * NE + j * 8;
    *(short8*)(qnor + row * QROW + j * 8) = *(const short8*)src;
  } else if (t < 512) {
    const int idx = t - 480;                 // zero-pad rows 30,31 (data cols only)
    const int row = 30 + (idx >> 4), j = idx & 15;
    *(short8*)(qnor + row * QROW + j * 8) = (short8){0,0,0,0,0,0,0,0};
  }
  __syncthreads();

  // ---- exact-match kernel (mu=1, sigma=0.001): integer ID equality ----
  if (t < ND) {
    const int did = doc[b * ND + t];
#pragma unroll 1
    for (int q = 0; q < NQ; ++q)
      if (did == qid[q]) atomicAdd(&Sex[q], 1.0f);   // all +1.0: order-invariant
  }

  // ---- per-lane A-fragment byte offsets into g_norm ----
  unsigned aoff[4];
#pragma unroll
  for (int dt = 0; dt < 4; ++dt) {
    const int id = doc[b * ND + dg * 64 + dt * 16 + lrow];
    aoff[dt] = (unsigned)id * (NE * 2) + lgrp * 16;
  }

  // ---- mm^T tile: C[d][q]; A from global table, B from LDS ----
  f32x4 acc[4];
#pragma unroll
  for (int dt = 0; dt < 4; ++dt) acc[dt] = (f32x4){0.f, 0.f, 0.f, 0.f};

  const unsigned char* gbase = (const unsigned char*)g_norm;
#pragma unroll
  for (int ks = 0; ks < 4; ++ks) {
    short8 bq = *(const short8*)(qnor + (qt * 16 + lrow) * QROW + ks * 32 + lgrp * 8);
#pragma unroll
    for (int dt = 0; dt < 4; ++dt) {
      short8 a = *(const short8*)(gbase + aoff[dt] + ks * 64);
      acc[dt] = __builtin_amdgcn_mfma_f32_16x16x32_bf16(a, bq, acc[dt], 0, 0, 0);
    }
  }

  // ---- kernel pooling: s_k = 2^{Cc*mu^2} * sum_d exp2(fma(m, bk, Cc*m^2)) ----
  const float Cc = -72.13475204444817f;  // -1/(2*0.1^2*ln2)
  float m[16], P[16];
#pragma unroll
  for (int dt = 0; dt < 4; ++dt)
#pragma unroll
    for (int r = 0; r < 4; ++r) {
      m[dt * 4 + r] = acc[dt][r];
      P[dt * 4 + r] = m[dt * 4 + r] * m[dt * 4 + r] * Cc;
    }
#pragma unroll 1
  for (int k = 0; k < 20; ++k) {
    const float mu  = fmaf(0.1f, (float)k, -0.95f);
    const float bk  = -2.0f * Cc * mu;
    const float sck = __builtin_amdgcn_exp2f(Cc * mu * mu);
    float s0 = 0.f, s1 = 0.f, s2 = 0.f, s3 = 0.f;
#pragma unroll
    for (int i = 0; i < 16; i += 4) {
      s0 += __builtin_amdgcn_exp2f(fmaf(m[i    ], bk, P[i    ]));
      s1 += __builtin_amdgcn_exp2f(fmaf(m[i + 1], bk, P[i + 1]));
      s2 += __builtin_amdgcn_exp2f(fmaf(m[i + 2], bk, P[i + 2]));
      s3 += __builtin_amdgcn_exp2f(fmaf(m[i + 3], bk, P[i + 3]));
    }
    float s = (s0 + s1) + (s2 + s3);
    s += __shfl_xor(s, 16);
    s += __shfl_xor(s, 32);
    if (lgrp == 0) Sw[wave][lrow][k] = s * sck;
  }
  __syncthreads();

  // ---- epilogue: km = sum_q log1p(S), then MLP 21->10->5->1 ----
  if (t < NK) {
    const int k = t;
    float s = 0.f;
    if (k < 20) {
      for (int q = 0; q < NQ; ++q) {
        const int w0 = (q >> 4);            // 0 for q<16 else 1
        float v = 0.f;
#pragma unroll
        for (int g = 0; g < 8; ++g) v += Sw[g * 2 + w0][q & 15][k];
        s += log1pf(v);
      }
    } else {
      for (int q = 0; q < NQ; ++q) s += log1pf(Sex[q]);
    }
    km[k] = s;
  }
  __syncthreads();
  if (t < 10) {
    float a = b1[t];
#pragma unroll 1
    for (int k2 = 0; k2 < NK; ++k2) a = fmaf(km[k2], w1[k2 * 10 + t], a);
    h1[t] = fmaxf(a, 0.f);
  }
  __syncthreads();
  if (t < 5) {
    float a = b2[t];
#pragma unroll 1
    for (int k2 = 0; k2 < 10; ++k2) a = fmaf(h1[k2], w2[k2 * 5 + t], a);
    h2[t] = fmaxf(a, 0.f);
  }
  __syncthreads();
  if (t == 0) {
    float a = b3[0];
#pragma unroll 1
    for (int k2 = 0; k2 < 5; ++k2) a = fmaf(h2[k2], w3[k2], a);
    out[b] = a;
  }
}

extern "C" void kernel_launch(void* const* d_in, const int* in_sizes, int n_in,
                              void* d_out, int out_size, void* d_ws, size_t ws_size,
                              hipStream_t stream) {
  const int*   query = (const int*)d_in[0];
  const int*   doc   = (const int*)d_in[1];
  const float* emb   = (const float*)d_in[2];
  const float* w1    = (const float*)d_in[3];
  const float* b1    = (const float*)d_in[4];
  const float* w2    = (const float*)d_in[5];
  const float* b2    = (const float*)d_in[6];
  const float* w3    = (const float*)d_in[7];
  const float* b3    = (const float*)d_in[8];
  float* out = (float*)d_out;

  norm_kernel<<<dim3(VOCAB / 8), dim3(256), 0, stream>>>(emb);
  knrm_main<<<dim3(NB), dim3(1024), 0, stream>>>(
      query, doc, w1, b1, w2, b2, w3, b3, out);
}

// Round 4
// 65.902 us; speedup vs baseline: 1.4792x; 1.1698x over previous
//
#include <hip/hip_runtime.h>
#include <hip/hip_bf16.h>
#include <math.h>

#define NB 512
#define NQ 30
#define ND 512
#define NE 128
#define NK 21
#define VOCAB 50000

typedef __attribute__((ext_vector_type(4))) float f32x4;
typedef __attribute__((ext_vector_type(8))) short short8;

// normalized vocab table, bf16 (12.8 MB). Rewritten every launch.
__device__ unsigned short g_norm[(size_t)VOCAB * NE];
// partial kernel sums S[b][q][k], accumulated by knrm_part, consumed by finish.
__device__ float g_S[(size_t)NB * 32 * NK];

__device__ __forceinline__ unsigned short f2bf(float f) {
  unsigned int x = __builtin_bit_cast(unsigned int, f);
  x = (x + 0x7fffu + ((x >> 16) & 1u)) >> 16;   // RNE
  return (unsigned short)x;
}

// ---------------- kernel 1: normalize whole vocab to bf16 + zero g_S ----------------
__global__ __launch_bounds__(256) void norm_kernel(const float* __restrict__ emb) {
  const int t = threadIdx.x;
  const int gid = blockIdx.x * 256 + t;
  if (gid < NB * 32 * NK) g_S[gid] = 0.0f;     // grid has 1.6M threads >= 344064
  const int row = blockIdx.x * 8 + (t >> 5);
  const int j = t & 31;
  const float* src = emb + (size_t)row * NE;
  float4 v = *(const float4*)(src + j * 4);
  float ssq = v.x * v.x + v.y * v.y + v.z * v.z + v.w * v.w;
  ssq += __shfl_xor(ssq, 1);
  ssq += __shfl_xor(ssq, 2);
  ssq += __shfl_xor(ssq, 4);
  ssq += __shfl_xor(ssq, 8);
  ssq += __shfl_xor(ssq, 16);
  const float sc = 1.0f / fmaxf(sqrtf(ssq), 1e-12f);
  ushort4 o;
  o.x = f2bf(v.x * sc); o.y = f2bf(v.y * sc);
  o.z = f2bf(v.z * sc); o.w = f2bf(v.w * sc);
  *(ushort4*)(g_norm + (size_t)row * NE + j * 4) = o;
}

// ---------------- kernel 2: partial KNRM (256 doc rows x 32 q per block) ----------------
// grid 1024 = (b, dhalf); 1024 threads = 16 waves; wave w: qt=w&1, dg=w>>1 (32 rows).
__global__ __launch_bounds__(1024, 8) void knrm_part(
    const int* __restrict__ query, const int* __restrict__ doc)
{
  extern __shared__ unsigned char smem_raw[];
  unsigned short* dtile = (unsigned short*)smem_raw;      // [256][128] bf16, 16B-slot swizzled
  unsigned short* qtile = dtile + 256 * NE;               // [32][128]  bf16, swizzled
  int* qid = (int*)(qtile + 32 * NE);                     // [32]

  const int t = threadIdx.x;
  // XCD swizzle: dispatch d -> work (d%8)*128 + d/8; XCD x gets contiguous 64 b's.
  const unsigned bid = blockIdx.x;
  const unsigned swz = (bid & 7) * 128 + (bid >> 3);
  const int b  = swz >> 1;
  const int d0 = (swz & 1) * 256;

  if (t < 32) qid[t] = (t < NQ) ? query[b * NQ + t] : -1;

  const int srow = t >> 4, slot = t & 15;
  // ---- stage 256 doc rows: 4 rounds x (64 rows x 16 lanes x 16B) ----
  short8 pay[4];
#pragma unroll
  for (int rnd = 0; rnd < 4; ++rnd) {
    const int r = rnd * 64 + srow;
    const int id = doc[b * ND + d0 + r];
    pay[rnd] = *(const short8*)(g_norm + (size_t)id * NE + slot * 8);
  }
#pragma unroll
  for (int rnd = 0; rnd < 4; ++rnd) {
    const int r = rnd * 64 + srow;
    *(short8*)(dtile + r * NE + ((slot ^ (r & 7)) * 8)) = pay[rnd];
  }
  // ---- stage 32 query rows (30 real + 2 zero) ----
  if (t < 512) {
    short8 qv = (short8){0, 0, 0, 0, 0, 0, 0, 0};
    if (srow < NQ)
      qv = *(const short8*)(g_norm + (size_t)query[b * NQ + srow] * NE + slot * 8);
    *(short8*)(qtile + srow * NE + ((slot ^ (srow & 7)) * 8)) = qv;
  }
  __syncthreads();

  // ---- exact-match kernel (mu=1, sigma=0.001): integer ID equality ----
  if (t < 256) {
    const int did = doc[b * ND + d0 + t];
#pragma unroll 1
    for (int q = 0; q < NQ; ++q)
      if (did == qid[q]) atomicAdd(&g_S[((size_t)b * 32 + q) * NK + 20], 1.0f);
  }

  const int wave = t >> 6, lane = t & 63;
  const int lrow = lane & 15, lgrp = lane >> 4;
  const int qt = wave & 1, dg = wave >> 1;

  // ---- mm^T tile: C[d][q]; A and B from swizzled LDS ----
  f32x4 acc[2];
  acc[0] = (f32x4){0.f, 0.f, 0.f, 0.f};
  acc[1] = (f32x4){0.f, 0.f, 0.f, 0.f};
  const int qrow = qt * 16 + lrow;
#pragma unroll
  for (int ks = 0; ks < 4; ++ks) {
    const int qs = (ks * 4 + lgrp) ^ (qrow & 7);
    short8 bq = *(const short8*)(qtile + qrow * NE + qs * 8);
#pragma unroll
    for (int dt = 0; dt < 2; ++dt) {
      const int R = dg * 32 + dt * 16 + lrow;
      const int as = (ks * 4 + lgrp) ^ (R & 7);
      short8 a = *(const short8*)(dtile + R * NE + as * 8);
      acc[dt] = __builtin_amdgcn_mfma_f32_16x16x32_bf16(a, bq, acc[dt], 0, 0, 0);
    }
  }
  __syncthreads();   // all dtile reads done -> safe to reuse as Sw

  float* Sw = (float*)dtile;   // [16 waves][16 lrow][20 k] = 20.5 KB
  const float Cc = -72.13475204444817f;  // -1/(2*0.1^2*ln2)
  float m[8], P[8];
#pragma unroll
  for (int dt = 0; dt < 2; ++dt)
#pragma unroll
    for (int r = 0; r < 4; ++r) {
      m[dt * 4 + r] = acc[dt][r];
      P[dt * 4 + r] = m[dt * 4 + r] * m[dt * 4 + r] * Cc;
    }
#pragma unroll 2
  for (int k = 0; k < 20; ++k) {
    const float mu  = fmaf(0.1f, (float)k, -0.95f);
    const float bk  = -2.0f * Cc * mu;
    const float sck = __builtin_amdgcn_exp2f(Cc * mu * mu);
    float s0 = 0.f, s1 = 0.f;
#pragma unroll
    for (int i = 0; i < 8; i += 2) {
      s0 += __builtin_amdgcn_exp2f(fmaf(m[i    ], bk, P[i    ]));
      s1 += __builtin_amdgcn_exp2f(fmaf(m[i + 1], bk, P[i + 1]));
    }
    float s = s0 + s1;
    s += __shfl_xor(s, 16);
    s += __shfl_xor(s, 32);
    if (lgrp == 0) Sw[(wave * 16 + lrow) * 20 + k] = s * sck;
  }
  __syncthreads();

  // ---- block reduce over 8 dg-waves, 2 atomics/(b,q,k) total ----
  if (t < 640) {
    const int q = t / 20, k = t % 20;
    const int w0 = q >> 4;                 // qt parity matching this q
    float v = 0.f;
#pragma unroll
    for (int g = 0; g < 8; ++g) v += Sw[((2 * g + w0) * 16 + (q & 15)) * 20 + k];
    atomicAdd(&g_S[((size_t)b * 32 + q) * NK + k], v);
  }
}

// ---------------- kernel 3: log1p + MLP ----------------
__global__ __launch_bounds__(64) void knrm_finish(
    const float* __restrict__ w1, const float* __restrict__ b1,
    const float* __restrict__ w2, const float* __restrict__ b2,
    const float* __restrict__ w3, const float* __restrict__ b3,
    float* __restrict__ out)
{
  __shared__ float km[NK], h1[10], h2[5];
  const int b = blockIdx.x, t = threadIdx.x;
  if (t < NK) {
    float s = 0.f;
    for (int q = 0; q < NQ; ++q) s += log1pf(g_S[((size_t)b * 32 + q) * NK + t]);
    km[t] = s;
  }
  __syncthreads();
  if (t < 10) {
    float a = b1[t];
#pragma unroll 1
    for (int k = 0; k < NK; ++k) a = fmaf(km[k], w1[k * 10 + t], a);
    h1[t] = fmaxf(a, 0.f);
  }
  __syncthreads();
  if (t < 5) {
    float a = b2[t];
#pragma unroll 1
    for (int k = 0; k < 10; ++k) a = fmaf(h1[k], w2[k * 5 + t], a);
    h2[t] = fmaxf(a, 0.f);
  }
  __syncthreads();
  if (t == 0) {
    float a = b3[0];
#pragma unroll 1
    for (int k = 0; k < 5; ++k) a = fmaf(h2[k], w3[k], a);
    out[b] = a;
  }
}

extern "C" void kernel_launch(void* const* d_in, const int* in_sizes, int n_in,
                              void* d_out, int out_size, void* d_ws, size_t ws_size,
                              hipStream_t stream) {
  const int*   query = (const int*)d_in[0];
  const int*   doc   = (const int*)d_in[1];
  const float* emb   = (const float*)d_in[2];
  const float* w1    = (const float*)d_in[3];
  const float* b1    = (const float*)d_in[4];
  const float* w2    = (const float*)d_in[5];
  const float* b2    = (const float*)d_in[6];
  const float* w3    = (const float*)d_in[7];
  const float* b3    = (const float*)d_in[8];
  float* out = (float*)d_out;

  const size_t sh = (size_t)256 * NE * 2    // dtile
                  + (size_t)32 * NE * 2     // qtile
                  + 32 * 4;                 // qid
  hipFuncSetAttribute((const void*)knrm_part,
                      hipFuncAttributeMaxDynamicSharedMemorySize, (int)sh);

  norm_kernel<<<dim3(VOCAB / 8), dim3(256), 0, stream>>>(emb);
  knrm_part<<<dim3(NB * 2), dim3(1024), sh, stream>>>(query, doc);
  knrm_finish<<<dim3(NB), dim3(64), 0, stream>>>(w1, b1, w2, b2, w3, b3, out);
}